// Round 1
// baseline (1152.169 us; speedup 1.0000x reference)
//
#include <hip/hip_runtime.h>

// LinearRegressionHospi: per-batch OLS fit over last W=30 timesteps of feature 0,
// extrapolate NF=14 steps. B=1e6, T=60, F=4, fp32.
//
// Memory-bound: needed bytes = 480 B/batch read (strided-16B floats force the
// whole span to be fetched) + 56 B/batch write. Roofline ~85 us at 6.3 TB/s.

#define NBATCH 256   // batches per block (== blockDim.x)
#define W      30    // window_size
#define NF     14    // n_forecast
#define TDIM   60    // T
#define ROWPAD 31    // W+1: LDS row stride (31 coprime 32 -> 2-way banks, free)

__global__ __launch_bounds__(256)
void linreg_forecast_kernel(const float4* __restrict__ in4,
                            float4* __restrict__ out4,
                            int B, int out4_total)
{
    __shared__ float y[NBATCH * ROWPAD];   // 256*31*4 = 31,744 B
    __shared__ float res[NBATCH * NF];     // 256*14*4 = 14,336 B

    const int tid = threadIdx.x;
    const int B0  = blockIdx.x * NBATCH;

    // ---- Phase 1: coalesced global->LDS load of y = inputs[b, 30:60, 0] ----
    // i = tid + 256k over [0, 256*30): consecutive lanes -> consecutive t
    // within a batch -> each wave-load covers ~3 contiguous 480B runs.
    #pragma unroll 5
    for (int k = 0; k < W; ++k) {          // 256*30/256 = 30 iters
        int i  = tid + (k << 8);
        int bb = i / W;                    // magic-mul division
        int t  = i - bb * W;
        int gb = B0 + bb;
        if (gb < B) {
            float4 v = in4[gb * TDIM + W + t];   // row (gb, 30+t, 0..3)
            y[bb * ROWPAD + t] = v.x;            // keep feature 0
        }
    }
    __syncthreads();

    // ---- Phase 2: per-thread OLS fit for batch B0+tid ----
    {
        int gb = B0 + tid;
        if (gb < B) {
            const float* row = &y[tid * ROWPAD];
            float s0 = 0.f, s1 = 0.f;
            #pragma unroll
            for (int t = 0; t < W; ++t) {
                float v = row[t];
                s0 += v;
                s1 += v * ((float)t - 14.5f);    // xc = t - x_mean
            }
            // sxx = sum((t-14.5)^2, t=0..29) = 2247.5
            float slope     = s1 * (1.0f / 2247.5f);
            float intercept = s0 * (1.0f / 30.0f) - slope * 14.5f;
            float* r = &res[tid * NF];
            #pragma unroll
            for (int j = 0; j < NF; ++j)
                r[j] = intercept + slope * (float)(W + j);  // t_future = 30..43
        }
    }
    __syncthreads();

    // ---- Phase 3: coalesced float4 store of this block's 3584 outputs ----
    const int base4 = blockIdx.x * (NBATCH * NF / 4);   // 896 float4 / block
    #pragma unroll
    for (int k = 0; k < 4; ++k) {
        int i = tid + (k << 8);
        if (i < NBATCH * NF / 4 && base4 + i < out4_total) {
            float4 v;
            v.x = res[4 * i + 0];
            v.y = res[4 * i + 1];
            v.z = res[4 * i + 2];
            v.w = res[4 * i + 3];
            out4[base4 + i] = v;
        }
    }
}

extern "C" void kernel_launch(void* const* d_in, const int* in_sizes, int n_in,
                              void* d_out, int out_size, void* d_ws, size_t ws_size,
                              hipStream_t stream)
{
    const float* in = (const float*)d_in[0];
    float*      out = (float*)d_out;
    int B = in_sizes[0] / (TDIM * 4);          // 1,000,000
    int grid = (B + NBATCH - 1) / NBATCH;      // 3907 blocks
    linreg_forecast_kernel<<<grid, 256, 0, stream>>>(
        (const float4*)in, (float4*)out, B, out_size / 4);
}